// Round 9
// baseline (172.780 us; speedup 1.0000x reference)
//
#include <hip/hip_runtime.h>
#include <hip/hip_bf16.h>
#include <math.h>

#define TKN 16384
#define HID 4096
#define NE  256
#define TOPK 8
#define NGRP 8
#define TOPG 4

#define BM 64
#define BK 64
#define NKT (HID / BK)          // 64 K-steps
#define BIMG 16384              // prep'd B image per (cb,kt): 8 frags x [hi 1K][lo 1K]

typedef _Float16 half8 __attribute__((ext_vector_type(8)));
typedef float    f32x4 __attribute__((ext_vector_type(4)));

static __device__ __forceinline__ unsigned pkrtz(float x, float y) {
    auto r = __builtin_amdgcn_cvt_pkrtz(x, y);   // v_cvt_pkrtz_f16_f32
    return __builtin_bit_cast(unsigned, r);
}
static __device__ __forceinline__ float hi_mask(float a) {
    return __uint_as_float(__float_as_uint(a) & 0xFFFFE000u);
}
// async global->LDS, 16B per lane; LDS dest = base + lane*16 (wave-uniform base)
static __device__ __forceinline__ void gload_lds16(const void* g, void* l) {
    __builtin_amdgcn_global_load_lds(
        (const __attribute__((address_space(1))) unsigned int*)g,
        (__attribute__((address_space(3))) unsigned int*)l, 16, 0, 0);
}

// ---- prep: B [256][4096] f32 -> FRAGMENT-ORDERED f16 hi/lo images ----------
// (verbatim round 8 — validated) wave fragment load = base + lane*16.
__global__ __launch_bounds__(256) void prep_b(const float* __restrict__ B,
                                              unsigned char* __restrict__ ws)
{
    const int gid = blockIdx.x * 256 + threadIdx.x;   // 131072
    const int e   = gid >> 9;          // expert 0..255
    const int k0  = (gid & 511) * 8;   // k chunk of 8
    const float* src = B + (size_t)e * HID + k0;
    float v[8];
    #pragma unroll
    for (int i = 0; i < 8; ++i) v[i] = src[i];
    unsigned hw[4], lw[4];
    #pragma unroll
    for (int j = 0; j < 4; ++j) {
        const float x0 = v[2*j], x1 = v[2*j+1];
        const float h0 = hi_mask(x0), h1 = hi_mask(x1);
        hw[j] = pkrtz(h0, h1);
        lw[j] = pkrtz(x0 - h0, x1 - h1);
    }
    const int cb     = e >> 6;
    const int colgrp = (e & 63) >> 4;
    const int lane16 = e & 15;
    const int kt     = k0 >> 6;
    const int kk     = k0 & 63;
    const int wg     = kk >> 5;
    const int kseg   = (kk >> 3) & 3;
    const int f      = colgrp * 2 + wg;
    unsigned char* img = ws + (size_t)(cb * NKT + kt) * BIMG
                            + f * 2048 + (kseg * 16 + lane16) * 16;
    *(uint4*)(img)        = make_uint4(hw[0], hw[1], hw[2], hw[3]);
    *(uint4*)(img + 1024) = make_uint4(lw[0], lw[1], lw[2], lw[3]);
}

// ---- GEMM: logits = A[T,H] @ B[E,H]^T, f16x2 split, 3 MFMA passes ----------
// m97-style structure: 64-row tile, 4 waves, 4 blocks/CU, async
// global_load_lds staging of RAW fp32 A (source pre-swizzled, LDS linear),
// consumer-side split (identical hi_mask/pkrtz ops -> bit-identical f16),
// B register-prefetched from the L2-resident fragment image.
// Per-accumulator MFMA chain + split-K epilogue add bit-identical to r3/5/6/8.
__global__ __launch_bounds__(256, 4) void gemm_mfma(
    const float* __restrict__ A, const unsigned char* __restrict__ Bws,
    float* __restrict__ C)
{
    // [buf][64 rows x 256 B raw fp32 A, XOR-swizzled via source permutation]
    __shared__ __align__(16) unsigned char smem[2][16384];   // 32 KiB

    const int tid  = threadIdx.x;
    const int lane = tid & 63;
    const int wave = tid >> 6;          // 0..3
    const int wg = wave >> 1;           // split-K half
    const int wc = wave & 1;            // col 32-half

    // XCD-bijective remap: cb-quads (same A panel) adjacent on one XCD
    const int logical = (blockIdx.x & 7) * 128 + (blockIdx.x >> 3);
    const int mb   = logical >> 2;      // 0..255
    const int cb   = logical & 3;       // 0..3
    const int row0 = mb * BM;

    // --- A staging via global_load_lds: wave stages rows [16w, 16w+16) ------
    // instr i covers rows 16w+4i+(lane>>4); lane chunk c=(lane&15)*16;
    // source col pre-swizzled by ((row&7)<<4) so LDS-linear == swizzled image.
    const unsigned char* Abytes = (const unsigned char*)A;
    const unsigned char* srcp[4];
    #pragma unroll
    for (int i = 0; i < 4; ++i) {
        const int row = 16 * wave + 4 * i + (lane >> 4);
        srcp[i] = Abytes + (size_t)(row0 + row) * (HID * 4)
                         + (((lane & 15) * 16) ^ ((row & 7) << 4));
    }
    const int ldsW = wave * 4096;   // wave's 16-row slab within a buffer

    // --- A fragment read addressing (consumer side) -------------------------
    // raw floats wg*32 + (lane>>4)*8 of row mt*16+(lane&15); 2x16B chunks.
    const int laneA0 = (lane & 15) * 256 +
                       ((wg * 128 + (lane >> 4) * 32) ^ ((lane & 7) << 4));
    const int laneA1 = laneA0 ^ 16;

    // --- B fragment offsets (verbatim r8) -----------------------------------
    const unsigned char* bBase = Bws + (size_t)cb * NKT * BIMG;
    const int f0off = ((wc * 2 + 0) * 2 + wg) * 2048 + lane * 16;
    const int f1off = ((wc * 2 + 1) * 2 + wg) * 2048 + lane * 16;

    f32x4 acc[4][2];
    #pragma unroll
    for (int i = 0; i < 4; ++i) { acc[i][0] = (f32x4)0.f; acc[i][1] = (f32x4)0.f; }

    half8 bC[4], bN[4];   // [bh0, bl0, bh1, bl1] current / next

    // prologue: stage A kt=0 into buf 0; B frags kt=0 into regs
    #pragma unroll
    for (int i = 0; i < 4; ++i)
        gload_lds16(srcp[i], &smem[0][ldsW + i * 1024]);
    bC[0] = *(const half8*)(bBase + f0off);
    bC[1] = *(const half8*)(bBase + f0off + 1024);
    bC[2] = *(const half8*)(bBase + f1off);
    bC[3] = *(const half8*)(bBase + f1off + 1024);
    __syncthreads();

#define GSTEP(KT, BCUR, BNXT)                                                  \
    {                                                                          \
        const int kt_ = (KT);                                                  \
        const unsigned char* ub = &smem[kt_ & 1][0];                           \
        const bool more = (kt_ != NKT - 1);                                    \
        if (more) {  /* async-stage A kt+1 into other buf; prefetch B */       \
            unsigned char* nb = &smem[(kt_ + 1) & 1][0];                       \
            _Pragma("unroll")                                                  \
            for (int i = 0; i < 4; ++i)                                        \
                gload_lds16(srcp[i] + (size_t)(kt_ + 1) * 256,                 \
                            nb + ldsW + i * 1024);                             \
            const unsigned char* bp = bBase + (size_t)(kt_ + 1) * BIMG;        \
            BNXT[0] = *(const half8*)(bp + f0off);                             \
            BNXT[1] = *(const half8*)(bp + f0off + 1024);                      \
            BNXT[2] = *(const half8*)(bp + f1off);                             \
            BNXT[3] = *(const half8*)(bp + f1off + 1024);                      \
        }                                                                      \
        __builtin_amdgcn_sched_barrier(0);                                     \
        _Pragma("unroll")                                                      \
        for (int mt = 0; mt < 4; ++mt) {                                       \
            const float4 u0 = *(const float4*)(ub + laneA0 + mt * 4096);       \
            const float4 u1 = *(const float4*)(ub + laneA1 + mt * 4096);       \
            const float h0 = hi_mask(u0.x), h1 = hi_mask(u0.y),                \
                        h2 = hi_mask(u0.z), h3 = hi_mask(u0.w);                \
            const float h4 = hi_mask(u1.x), h5 = hi_mask(u1.y),                \
                        h6 = hi_mask(u1.z), h7 = hi_mask(u1.w);                \
            unsigned ahw[4], alw[4];                                           \
            ahw[0] = pkrtz(h0, h1);            ahw[1] = pkrtz(h2, h3);         \
            ahw[2] = pkrtz(h4, h5);            ahw[3] = pkrtz(h6, h7);         \
            alw[0] = pkrtz(u0.x - h0, u0.y - h1);                              \
            alw[1] = pkrtz(u0.z - h2, u0.w - h3);                              \
            alw[2] = pkrtz(u1.x - h4, u1.y - h5);                              \
            alw[3] = pkrtz(u1.z - h6, u1.w - h7);                              \
            const half8 ah = __builtin_bit_cast(half8,                         \
                make_uint4(ahw[0], ahw[1], ahw[2], ahw[3]));                   \
            const half8 al = __builtin_bit_cast(half8,                         \
                make_uint4(alw[0], alw[1], alw[2], alw[3]));                   \
            f32x4 c0 = acc[mt][0];                                             \
            c0 = __builtin_amdgcn_mfma_f32_16x16x32_f16(ah, BCUR[0], c0, 0, 0, 0); \
            c0 = __builtin_amdgcn_mfma_f32_16x16x32_f16(ah, BCUR[1], c0, 0, 0, 0); \
            c0 = __builtin_amdgcn_mfma_f32_16x16x32_f16(al, BCUR[0], c0, 0, 0, 0); \
            acc[mt][0] = c0;                                                   \
            f32x4 c1 = acc[mt][1];                                             \
            c1 = __builtin_amdgcn_mfma_f32_16x16x32_f16(ah, BCUR[2], c1, 0, 0, 0); \
            c1 = __builtin_amdgcn_mfma_f32_16x16x32_f16(ah, BCUR[3], c1, 0, 0, 0); \
            c1 = __builtin_amdgcn_mfma_f32_16x16x32_f16(al, BCUR[2], c1, 0, 0, 0); \
            acc[mt][1] = c1;                                                   \
        }                                                                      \
        __syncthreads();                                                       \
    }

    for (int kt = 0; kt < NKT; kt += 2) {
        GSTEP(kt,     bC, bN);
        GSTEP(kt + 1, bN, bC);
    }
#undef GSTEP

    // epilogue: reduce wg1 into wg0 through LDS (same math as r3/5/6/8)
    float* redf = (float*)&smem[0][0];               // scratch (loop done)
    const int fb = wc * 2048 + lane * 4;             // float index
    if (wg == 1) {
        #pragma unroll
        for (int mt = 0; mt < 4; ++mt)
            #pragma unroll
            for (int nt = 0; nt < 2; ++nt)
                *(f32x4*)&redf[fb + (mt * 2 + nt) * 256] = acc[mt][nt];
    }
    __syncthreads();
    if (wg == 0) {
        #pragma unroll
        for (int mt = 0; mt < 4; ++mt) {
            #pragma unroll
            for (int nt = 0; nt < 2; ++nt) {
                f32x4 o = acc[mt][nt] + *(const f32x4*)&redf[fb + (mt * 2 + nt) * 256];
                const int r0 = row0 + mt * 16 + (lane >> 4) * 4;
                const int cc = cb * 64 + wc * 32 + nt * 16 + (lane & 15);
                #pragma unroll
                for (int r = 0; r < 4; ++r)
                    C[(size_t)(r0 + r) * NE + cc] = o[r];
            }
        }
    }
}

// ---------------- Router: per-token top-k (verified rounds 1-3, 5, 6, 8) ----
__global__ __launch_bounds__(256) void router_topk_kernel(
    const float* __restrict__ logits, const float* __restrict__ bias,
    float* __restrict__ out_w, float* __restrict__ out_i)
{
    const int wid  = threadIdx.x >> 6;
    const int lane = threadIdx.x & 63;
    const int token = blockIdx.x * 4 + wid;

    const float* row = logits + (size_t)token * NE;
    const float4 lg = *(const float4*)&row[lane * 4];

    float sig[4], sc[4];
    {
        const float l4[4] = {lg.x, lg.y, lg.z, lg.w};
        #pragma unroll
        for (int j = 0; j < 4; ++j) {
            sig[j] = 1.f / (1.f + expf(-l4[j]));
            sc[j]  = sig[j] + bias[lane * 4 + j];
        }
    }

    float m1 = sc[0], m2 = -INFINITY;
    #pragma unroll
    for (int j = 1; j < 4; ++j) {
        if (sc[j] > m1) { m2 = m1; m1 = sc[j]; }
        else if (sc[j] > m2) { m2 = sc[j]; }
    }
    #pragma unroll
    for (int off = 1; off < 8; off <<= 1) {
        const float o1 = __shfl_xor(m1, off);
        const float o2 = __shfl_xor(m2, off);
        const float lo = fminf(m1, o1);
        m1 = fmaxf(m1, o1);
        m2 = fmaxf(lo, fmaxf(m2, o2));
    }
    const float gscore = m1 + m2;

    const int gmy = lane >> 3;
    int rank = 0;
    #pragma unroll
    for (int g = 0; g < NGRP; ++g) {
        const float gs = __shfl(gscore, g * 8);
        if (gs > gscore || (gs == gscore && g < gmy)) ++rank;
    }
    if (rank >= TOPG) {
        #pragma unroll
        for (int j = 0; j < 4; ++j) sc[j] = -INFINITY;
    }

    float wk[TOPK]; int ik[TOPK];
    float wsum = 0.f;
    #pragma unroll
    for (int k = 0; k < TOPK; ++k) {
        float bv = sc[0]; int bi = lane * 4;
        #pragma unroll
        for (int j = 1; j < 4; ++j)
            if (sc[j] > bv) { bv = sc[j]; bi = lane * 4 + j; }
        #pragma unroll
        for (int off = 1; off < 64; off <<= 1) {
            const float v2 = __shfl_xor(bv, off);
            const int   i2 = __shfl_xor(bi, off);
            if (v2 > bv || (v2 == bv && i2 < bi)) { bv = v2; bi = i2; }
        }
        const int owner = bi >> 2;
        const int j = bi & 3;
        const float sv = (j == 0) ? sig[0] : (j == 1) ? sig[1] : (j == 2) ? sig[2] : sig[3];
        const float w = __shfl(sv, owner);
        wk[k] = w; ik[k] = bi; wsum += w;
        if (lane == owner) {
            if (j == 0) sc[0] = -INFINITY;
            else if (j == 1) sc[1] = -INFINITY;
            else if (j == 2) sc[2] = -INFINITY;
            else sc[3] = -INFINITY;
        }
    }

    if (lane == 0) {
        const float denom = wsum + 1e-20f;
        #pragma unroll
        for (int k = 0; k < TOPK; ++k) {
            out_w[(size_t)token * TOPK + k] = wk[k] / denom;
            out_i[(size_t)token * TOPK + k] = (float)ik[k];
        }
    }
}

extern "C" void kernel_launch(void* const* d_in, const int* in_sizes, int n_in,
                              void* d_out, int out_size, void* d_ws, size_t ws_size,
                              hipStream_t stream) {
    const float* hidden = (const float*)d_in[0];
    const float* weight = (const float*)d_in[1];
    const float* bias   = (const float*)d_in[2];

    float* logits = (float*)d_out;                              // [T, E]
    float* out_w  = logits + (size_t)TKN * NE;                  // [T, 8]
    float* out_i  = out_w + (size_t)TKN * TOPK;                 // [T, 8]

    unsigned char* bpl = (unsigned char*)d_ws;                  // 4 MB B images

    prep_b<<<512, 256, 0, stream>>>(weight, bpl);
    gemm_mfma<<<1024, 256, 0, stream>>>(hidden, bpl, logits);
    router_topk_kernel<<<TKN / 4, 256, 0, stream>>>(logits, bias, out_w, out_i);
}

// Round 10
// 169.949 us; speedup vs baseline: 1.0167x; 1.0167x over previous
//
#include <hip/hip_runtime.h>
#include <hip/hip_bf16.h>
#include <math.h>

#define TKN 16384
#define HID 4096
#define NE  256
#define TOPK 8
#define NGRP 8
#define TOPG 4

#define BM 64
#define BK 64
#define NKT (HID / BK)          // 64 K-steps
#define BIMG 16384              // prep'd B image per (cb,kt): 8 frags x [hi 1K][lo 1K]

typedef _Float16 half8 __attribute__((ext_vector_type(8)));
typedef float    f32x4 __attribute__((ext_vector_type(4)));

static __device__ __forceinline__ unsigned pkrtz(float x, float y) {
    auto r = __builtin_amdgcn_cvt_pkrtz(x, y);   // v_cvt_pkrtz_f16_f32
    return __builtin_bit_cast(unsigned, r);
}
static __device__ __forceinline__ float hi_mask(float a) {
    return __uint_as_float(__float_as_uint(a) & 0xFFFFE000u);
}
// split one float4 into hi/lo f16 pairs and write 8B to each plane.
// IDENTICAL value math to all passing rounds -> bit-identical MFMA inputs.
static __device__ __forceinline__ void split_w(const float4 v,
    unsigned char* hiP, unsigned char* loP, int ofs)
{
    const float h0 = hi_mask(v.x), h1 = hi_mask(v.y),
                h2 = hi_mask(v.z), h3 = hi_mask(v.w);
    *(uint2*)(hiP + ofs) = make_uint2(pkrtz(h0, h1), pkrtz(h2, h3));
    *(uint2*)(loP + ofs) = make_uint2(pkrtz(v.x - h0, v.y - h1),
                                      pkrtz(v.z - h2, v.w - h3));
}

// ---- prep: B [256][4096] f32 -> FRAGMENT-ORDERED f16 hi/lo images ----------
// (verbatim rounds 8/9 — validated) wave fragment load = base + lane*16.
__global__ __launch_bounds__(256) void prep_b(const float* __restrict__ B,
                                              unsigned char* __restrict__ ws)
{
    const int gid = blockIdx.x * 256 + threadIdx.x;   // 131072
    const int e   = gid >> 9;          // expert 0..255
    const int k0  = (gid & 511) * 8;   // k chunk of 8
    const float* src = B + (size_t)e * HID + k0;
    float v[8];
    #pragma unroll
    for (int i = 0; i < 8; ++i) v[i] = src[i];
    unsigned hw[4], lw[4];
    #pragma unroll
    for (int j = 0; j < 4; ++j) {
        const float x0 = v[2*j], x1 = v[2*j+1];
        const float h0 = hi_mask(x0), h1 = hi_mask(x1);
        hw[j] = pkrtz(h0, h1);
        lw[j] = pkrtz(x0 - h0, x1 - h1);
    }
    const int cb     = e >> 6;
    const int colgrp = (e & 63) >> 4;
    const int lane16 = e & 15;
    const int kt     = k0 >> 6;
    const int kk     = k0 & 63;
    const int wg     = kk >> 5;
    const int kseg   = (kk >> 3) & 3;
    const int f      = colgrp * 2 + wg;
    unsigned char* img = ws + (size_t)(cb * NKT + kt) * BIMG
                            + f * 2048 + (kseg * 16 + lane16) * 16;
    *(uint4*)(img)        = make_uint4(hw[0], hw[1], hw[2], hw[3]);
    *(uint4*)(img + 1024) = make_uint4(lw[0], lw[1], lw[2], lw[3]);
}

// ---- GEMM: logits = A[T,H] @ B[E,H]^T, f16x2 split, 3 MFMA passes ----------
// Relaxed-barrier pipeline: per iter, issue A-raw(t+2)+B(t+1) register loads,
// then {lgkmcnt(0); s_barrier} (NO vmcnt drain -> loads live across barriers),
// then split A(t+1)->LDS buf[(t+1)&1], then ds_read buf[t&1] + MFMA(t).
// A LDS layout = r5/r6-proven conflict-free f16 planes (128B rows, XOR swz).
// Per-accumulator MFMA chain + split-K epilogue add bit-identical to r3..r9.
__global__ __launch_bounds__(256, 3) void gemm_mfma(
    const float* __restrict__ A, const unsigned char* __restrict__ Bws,
    float* __restrict__ C)
{
    // [buf][plane hi/lo][64 rows x 128 B]
    __shared__ __align__(16) unsigned char smem[2][2][8192];   // 32 KiB

    const int tid  = threadIdx.x;
    const int lane = tid & 63;
    const int wave = tid >> 6;          // 0..3
    const int wg = wave >> 1;           // split-K half
    const int wc = wave & 1;            // col 32-half

    // XCD-bijective remap: cb-quads (same A panel) adjacent on one XCD
    const int logical = (blockIdx.x & 7) * 128 + (blockIdx.x >> 3);
    const int mb   = logical >> 2;      // 0..255
    const int cb   = logical & 3;       // 0..3
    const int row0 = mb * BM;

    // A staging: thread's 4 chunks = rows i*16 + wave*4 + (lane>>4),
    // raw col floats (lane&15)*4 — each staged load is 1KB lane-contiguous.
    const float* srcp[4];
    int wofs[4];
    #pragma unroll
    for (int i = 0; i < 4; ++i) {
        const int r = i * 16 + wave * 4 + (lane >> 4);
        srcp[i] = A + (size_t)(row0 + r) * HID + (lane & 15) * 4;
        wofs[i] = r * 128 + (((lane & 15) * 8) ^ ((r & 7) << 4));
    }

    // A fragment read addressing (r5/r6-proven: 0 conflicts)
    const int kx    = ((wg * 64) + ((lane >> 4) << 4)) ^ ((lane & 7) << 4);
    const int aRowB = (lane & 15) * 128;

    // B fragment offsets (verbatim r8/r9)
    const unsigned char* bBase = Bws + (size_t)cb * NKT * BIMG;
    const int f0off = ((wc * 2 + 0) * 2 + wg) * 2048 + lane * 16;
    const int f1off = ((wc * 2 + 1) * 2 + wg) * 2048 + lane * 16;

    f32x4 acc[4][2];
    #pragma unroll
    for (int i = 0; i < 4; ++i) { acc[i][0] = (f32x4)0.f; acc[i][1] = (f32x4)0.f; }

    float4 aA[4], aB[4];      // raw A reg banks (2-deep rotation)
    half8  bA[4], bB[4];      // B frag banks (1-deep rotation)

    // prologue: tile 0 split->buf0 synchronously; A(1)->aB; B(0)->bA
    {
        float4 p[4];
        #pragma unroll
        for (int i = 0; i < 4; ++i) p[i] = *(const float4*)(srcp[i]);
        #pragma unroll
        for (int i = 0; i < 4; ++i)
            split_w(p[i], &smem[0][0][0], &smem[0][1][0], wofs[i]);
    }
    #pragma unroll
    for (int i = 0; i < 4; ++i) aB[i] = *(const float4*)(srcp[i] + BK);
    bA[0] = *(const half8*)(bBase + f0off);
    bA[1] = *(const half8*)(bBase + f0off + 1024);
    bA[2] = *(const half8*)(bBase + f1off);
    bA[3] = *(const half8*)(bBase + f1off + 1024);
    __syncthreads();

#define PSTEP(T, RBUF, WBUF, ASPL, AISS, BCUR, BNXT)                           \
    {                                                                          \
        const int t_ = (T);                                                    \
        if (t_ + 2 < NKT) {  /* issue A raw (HBM) 2 iters ahead */             \
            _Pragma("unroll")                                                  \
            for (int i = 0; i < 4; ++i)                                        \
                AISS[i] = *(const float4*)(srcp[i] + (t_ + 2) * BK);           \
        }                                                                      \
        if (t_ + 1 < NKT) {  /* issue B frags (L2) 1 iter ahead */             \
            const unsigned char* bp = bBase + (size_t)(t_ + 1) * BIMG;         \
            BNXT[0] = *(const half8*)(bp + f0off);                             \
            BNXT[1] = *(const half8*)(bp + f0off + 1024);                      \
            BNXT[2] = *(const half8*)(bp + f1off);                             \
            BNXT[3] = *(const half8*)(bp + f1off + 1024);                      \
        }                                                                      \
        /* relaxed barrier: LDS visibility only, NO vmcnt drain */             \
        asm volatile("s_waitcnt lgkmcnt(0)\n\ts_barrier" ::: "memory");        \
        if (t_ + 1 < NKT) {  /* split A(t+1) into the non-read buffer */       \
            _Pragma("unroll")                                                  \
            for (int i = 0; i < 4; ++i)                                        \
                split_w(ASPL[i], &WBUF[0][0], &WBUF[1][0], wofs[i]);           \
        }                                                                      \
        _Pragma("unroll")                                                      \
        for (int mt = 0; mt < 4; ++mt) {                                       \
            const half8 ah = *(const half8*)(&RBUF[0][0] + aRowB + mt * 2048 + kx); \
            const half8 al = *(const half8*)(&RBUF[1][0] + aRowB + mt * 2048 + kx); \
            f32x4 c0 = acc[mt][0];                                             \
            c0 = __builtin_amdgcn_mfma_f32_16x16x32_f16(ah, BCUR[0], c0, 0, 0, 0); \
            c0 = __builtin_amdgcn_mfma_f32_16x16x32_f16(ah, BCUR[1], c0, 0, 0, 0); \
            c0 = __builtin_amdgcn_mfma_f32_16x16x32_f16(al, BCUR[0], c0, 0, 0, 0); \
            acc[mt][0] = c0;                                                   \
            f32x4 c1 = acc[mt][1];                                             \
            c1 = __builtin_amdgcn_mfma_f32_16x16x32_f16(ah, BCUR[2], c1, 0, 0, 0); \
            c1 = __builtin_amdgcn_mfma_f32_16x16x32_f16(ah, BCUR[3], c1, 0, 0, 0); \
            c1 = __builtin_amdgcn_mfma_f32_16x16x32_f16(al, BCUR[3 - 1], c1, 0, 0, 0); \
            acc[mt][1] = c1;                                                   \
        }                                                                      \
    }

    for (int kt = 0; kt < NKT; kt += 2) {
        PSTEP(kt,     smem[0], smem[1], aB, aA, bA, bB);
        PSTEP(kt + 1, smem[1], smem[0], aA, aB, bB, bA);
    }
#undef PSTEP

    // epilogue: reduce wg1 into wg0 through LDS (verbatim r9 math), write C
    float* redf = (float*)&smem[0][0][0];            // buf0 (16 KB) scratch
    const int fb = wc * 2048 + lane * 4;             // float index
    if (wg == 1) {
        #pragma unroll
        for (int mt = 0; mt < 4; ++mt)
            #pragma unroll
            for (int nt = 0; nt < 2; ++nt)
                *(f32x4*)&redf[fb + (mt * 2 + nt) * 256] = acc[mt][nt];
    }
    __syncthreads();
    if (wg == 0) {
        #pragma unroll
        for (int mt = 0; mt < 4; ++mt) {
            #pragma unroll
            for (int nt = 0; nt < 2; ++nt) {
                f32x4 o = acc[mt][nt] + *(const f32x4*)&redf[fb + (mt * 2 + nt) * 256];
                const int r0 = row0 + mt * 16 + (lane >> 4) * 4;
                const int cc = cb * 64 + wc * 32 + nt * 16 + (lane & 15);
                #pragma unroll
                for (int r = 0; r < 4; ++r)
                    C[(size_t)(r0 + r) * NE + cc] = o[r];
            }
        }
    }
}

// ---------------- Router: per-token top-k (verified rounds 1-3, 5, 6, 8, 9) -
__global__ __launch_bounds__(256) void router_topk_kernel(
    const float* __restrict__ logits, const float* __restrict__ bias,
    float* __restrict__ out_w, float* __restrict__ out_i)
{
    const int wid  = threadIdx.x >> 6;
    const int lane = threadIdx.x & 63;
    const int token = blockIdx.x * 4 + wid;

    const float* row = logits + (size_t)token * NE;
    const float4 lg = *(const float4*)&row[lane * 4];

    float sig[4], sc[4];
    {
        const float l4[4] = {lg.x, lg.y, lg.z, lg.w};
        #pragma unroll
        for (int j = 0; j < 4; ++j) {
            sig[j] = 1.f / (1.f + expf(-l4[j]));
            sc[j]  = sig[j] + bias[lane * 4 + j];
        }
    }

    float m1 = sc[0], m2 = -INFINITY;
    #pragma unroll
    for (int j = 1; j < 4; ++j) {
        if (sc[j] > m1) { m2 = m1; m1 = sc[j]; }
        else if (sc[j] > m2) { m2 = sc[j]; }
    }
    #pragma unroll
    for (int off = 1; off < 8; off <<= 1) {
        const float o1 = __shfl_xor(m1, off);
        const float o2 = __shfl_xor(m2, off);
        const float lo = fminf(m1, o1);
        m1 = fmaxf(m1, o1);
        m2 = fmaxf(lo, fmaxf(m2, o2));
    }
    const float gscore = m1 + m2;

    const int gmy = lane >> 3;
    int rank = 0;
    #pragma unroll
    for (int g = 0; g < NGRP; ++g) {
        const float gs = __shfl(gscore, g * 8);
        if (gs > gscore || (gs == gscore && g < gmy)) ++rank;
    }
    if (rank >= TOPG) {
        #pragma unroll
        for (int j = 0; j < 4; ++j) sc[j] = -INFINITY;
    }

    float wk[TOPK]; int ik[TOPK];
    float wsum = 0.f;
    #pragma unroll
    for (int k = 0; k < TOPK; ++k) {
        float bv = sc[0]; int bi = lane * 4;
        #pragma unroll
        for (int j = 1; j < 4; ++j)
            if (sc[j] > bv) { bv = sc[j]; bi = lane * 4 + j; }
        #pragma unroll
        for (int off = 1; off < 64; off <<= 1) {
            const float v2 = __shfl_xor(bv, off);
            const int   i2 = __shfl_xor(bi, off);
            if (v2 > bv || (v2 == bv && i2 < bi)) { bv = v2; bi = i2; }
        }
        const int owner = bi >> 2;
        const int j = bi & 3;
        const float sv = (j == 0) ? sig[0] : (j == 1) ? sig[1] : (j == 2) ? sig[2] : sig[3];
        const float w = __shfl(sv, owner);
        wk[k] = w; ik[k] = bi; wsum += w;
        if (lane == owner) {
            if (j == 0) sc[0] = -INFINITY;
            else if (j == 1) sc[1] = -INFINITY;
            else if (j == 2) sc[2] = -INFINITY;
            else sc[3] = -INFINITY;
        }
    }

    if (lane == 0) {
        const float denom = wsum + 1e-20f;
        #pragma unroll
        for (int k = 0; k < TOPK; ++k) {
            out_w[(size_t)token * TOPK + k] = wk[k] / denom;
            out_i[(size_t)token * TOPK + k] = (float)ik[k];
        }
    }
}

extern "C" void kernel_launch(void* const* d_in, const int* in_sizes, int n_in,
                              void* d_out, int out_size, void* d_ws, size_t ws_size,
                              hipStream_t stream) {
    const float* hidden = (const float*)d_in[0];
    const float* weight = (const float*)d_in[1];
    const float* bias   = (const float*)d_in[2];

    float* logits = (float*)d_out;                              // [T, E]
    float* out_w  = logits + (size_t)TKN * NE;                  // [T, 8]
    float* out_i  = out_w + (size_t)TKN * TOPK;                 // [T, 8]

    unsigned char* bpl = (unsigned char*)d_ws;                  // 4 MB B images

    prep_b<<<512, 256, 0, stream>>>(weight, bpl);
    gemm_mfma<<<1024, 256, 0, stream>>>(hidden, bpl, logits);
    router_topk_kernel<<<TKN / 4, 256, 0, stream>>>(logits, bias, out_w, out_i);
}